// Round 1
// baseline (1162.484 us; speedup 1.0000x reference)
//
#include <hip/hip_runtime.h>
#include <hip/hip_bf16.h>

// Problem constants (fixed by setup_inputs)
#define D    128      // feature dim
#define NPM  64       // nodes per molecule
#define NMOL 256      // molecules (= grid size = 1 block per CU)
#define NTOT 16384    // total nodes
#define SK   136      // LDS stride for A-layout (row-major v, bf16 elems)
#define ST   72       // LDS stride for T-layout (col-major h) and adjacency
#define XPLANE 9216   // max(64*SK=8704, 128*ST=9216) — hi/lo planes are aliased A/T

typedef __attribute__((ext_vector_type(8))) short bf16x8;
typedef __attribute__((ext_vector_type(4))) float f32x4;

__device__ __forceinline__ unsigned short f2bf(float x){
    union { float f; unsigned u; } c; c.f = x;
    unsigned r = c.u + 0x7FFFu + ((c.u >> 16) & 1u);  // RNE to bf16
    return (unsigned short)(r >> 16);
}
__device__ __forceinline__ float bf2f(unsigned short h){
    union { float f; unsigned u; } c; c.u = ((unsigned)h) << 16;
    return c.f;
}
// reference's tanh-approx GELU; tanh(z) = 1 - 2/(exp(2z)+1) is robust at both tails
__device__ __forceinline__ float gelu_f(float x){
    float z = 0.7978845608028654f * (x + 0.044715f * x * x * x);
    float e = __expf(2.0f * z);
    float t = 1.0f - 2.0f / (e + 1.0f);
    return 0.5f * x * (1.0f + t);
}

// Split W_fp_w into bf16 hi/lo planes once per launch (ws is re-poisoned each call)
__global__ void prep_w_split(const float* __restrict__ W,
                             unsigned short* __restrict__ hi,
                             unsigned short* __restrict__ lo, int n){
    int i = blockIdx.x * blockDim.x + threadIdx.x;
    if (i < n){
        float x = W[i];
        unsigned short h = f2bf(x);
        hi[i] = h;
        lo[i] = f2bf(x - bf2f(h));
    }
}

__global__ __launch_bounds__(512)
void mgnn_kernel(const int*   __restrict__ fps,
                 const float* __restrict__ adjacency,
                 const float* __restrict__ embed,
                 const unsigned short* __restrict__ Whi,  // [3][128][128] bf16 hi
                 const unsigned short* __restrict__ Wlo,  // [3][128][128] bf16 lo
                 const float* __restrict__ Wfb,           // [3][128]
                 const float* __restrict__ Wout,          // [2][128][128]
                 const float* __restrict__ Wob,           // [2][128]
                 const float* __restrict__ masks,         // [256]
                 float* __restrict__ out)                 // [256][128]
{
    __shared__ __attribute__((aligned(16))) unsigned short sXhi[XPLANE];
    __shared__ __attribute__((aligned(16))) unsigned short sXlo[XPLANE];
    __shared__ __attribute__((aligned(16))) unsigned short sAdj[NPM * ST];
    __shared__ int   sFp[NPM];
    __shared__ float sSS[NPM * 2];
    __shared__ float sMolPart[4 * D];
    __shared__ __attribute__((aligned(16))) float sMolF[D];
    __shared__ __attribute__((aligned(16))) float sY[D];

    const int tid  = threadIdx.x;
    const int blk  = blockIdx.x;
    const int lane = tid & 63;
    const int wave = tid >> 6;     // 8 waves
    const int l15  = lane & 15;
    const int q    = lane >> 4;    // quad 0..3
    const int mt   = wave & 3;     // m-tile (rows 16*mt..16*mt+15)
    const int nh   = wave >> 2;    // n-half (cols 64*nh..64*nh+63, 4 n-tiles)
    const int base = blk * NPM;

    // ---- stage fingerprints + adjacency diagonal block (exact in bf16) ----
    if (tid < NPM) sFp[tid] = fps[base + tid];
    #pragma unroll
    for (int u = 0; u < 8; ++u){
        int idx = tid + 512 * u;              // 4096 = 64x64 elements
        int r = idx >> 6, c = idx & 63;
        float a = adjacency[(size_t)(base + r) * NTOT + (base + c)];
        sAdj[r * ST + c] = f2bf(a);           // 0.0/1.0 exact
    }
    __syncthreads();

    // ---- gather embeddings -> split bf16 hi/lo, A-layout [row][k] ----
    #pragma unroll
    for (int u = 0; u < 16; ++u){
        int idx = tid + 512 * u;              // 8192 = 64x128
        int r = idx >> 7, j = idx & 127;
        float v = embed[sFp[r] * D + j];
        unsigned short h = f2bf(v);
        sXhi[r * SK + j] = h;
        sXlo[r * SK + j] = f2bf(v - bf2f(h));
    }
    __syncthreads();

    const f32x4 zero4 = {0.f, 0.f, 0.f, 0.f};
    float vreg[4][4];                          // normalized v (for pooling)

    for (int l = 0; l < 3; ++l){
        // ---------- phase 1: H = v @ W^T (split-bf16, fp32 acc) ----------
        f32x4 acc[4] = {zero4, zero4, zero4, zero4};
        const int row_a = 16 * mt + l15;
        const unsigned short* WhiL = Whi + l * D * D;
        const unsigned short* WloL = Wlo + l * D * D;
        #pragma unroll
        for (int kt = 0; kt < 4; ++kt){
            int kb = kt * 32 + 8 * q;
            bf16x8 ahi = *(const bf16x8*)&sXhi[row_a * SK + kb];
            bf16x8 alo = *(const bf16x8*)&sXlo[row_a * SK + kb];
            #pragma unroll
            for (int tt = 0; tt < 4; ++tt){
                int n = 16 * (4 * nh + tt) + l15;
                bf16x8 bhi = *(const bf16x8*)&WhiL[n * D + kb];
                bf16x8 blo = *(const bf16x8*)&WloL[n * D + kb];
                acc[tt] = __builtin_amdgcn_mfma_f32_16x16x32_bf16(ahi, bhi, acc[tt], 0, 0, 0);
                acc[tt] = __builtin_amdgcn_mfma_f32_16x16x32_bf16(alo, bhi, acc[tt], 0, 0, 0);
                acc[tt] = __builtin_amdgcn_mfma_f32_16x16x32_bf16(ahi, blo, acc[tt], 0, 0, 0);
            }
        }
        __syncthreads();   // all A-layout reads done before T-layout overwrite

        // ---------- epilogue: h = gelu(H + b); keep fp32 in regs; write split-T ----------
        float hreg[4][4];
        #pragma unroll
        for (int tt = 0; tt < 4; ++tt){
            int j = 64 * nh + 16 * tt + l15;
            float bias = Wfb[l * D + j];
            #pragma unroll
            for (int reg = 0; reg < 4; ++reg){
                int i = 16 * mt + 4 * q + reg;
                float h = gelu_f(acc[tt][reg] + bias);
                hreg[tt][reg] = h;
                unsigned short hh = f2bf(h);
                sXhi[j * ST + i] = hh;                       // T-layout [col][node]
                sXlo[j * ST + i] = f2bf(h - bf2f(hh));
            }
        }
        __syncthreads();   // T-layout visible to all waves

        // ---------- phase 2: R = Adj @ h (Adj exact bf16; h split) ----------
        f32x4 racc[4] = {zero4, zero4, zero4, zero4};
        #pragma unroll
        for (int kt = 0; kt < 2; ++kt){
            int kb = kt * 32 + 8 * q;
            bf16x8 aadj = *(const bf16x8*)&sAdj[(16 * mt + l15) * ST + kb];
            #pragma unroll
            for (int tt = 0; tt < 4; ++tt){
                int n = 16 * (4 * nh + tt) + l15;
                bf16x8 bhi = *(const bf16x8*)&sXhi[n * ST + kb];
                bf16x8 blo = *(const bf16x8*)&sXlo[n * ST + kb];
                racc[tt] = __builtin_amdgcn_mfma_f32_16x16x32_bf16(aadj, bhi, racc[tt], 0, 0, 0);
                racc[tt] = __builtin_amdgcn_mfma_f32_16x16x32_bf16(aadj, blo, racc[tt], 0, 0, 0);
            }
        }

        // ---------- o = h + R; row sum-of-squares ----------
        float o[4][4];
        float p[4] = {0.f, 0.f, 0.f, 0.f};
        #pragma unroll
        for (int tt = 0; tt < 4; ++tt)
            #pragma unroll
            for (int reg = 0; reg < 4; ++reg){
                float v = hreg[tt][reg] + racc[tt][reg];
                o[tt][reg] = v;
                p[reg] += v * v;
            }
        #pragma unroll
        for (int d2 = 1; d2 <= 8; d2 <<= 1)
            #pragma unroll
            for (int reg = 0; reg < 4; ++reg)
                p[reg] += __shfl_xor(p[reg], d2);
        if (l15 == 0){
            #pragma unroll
            for (int reg = 0; reg < 4; ++reg)
                sSS[(16 * mt + 4 * q + reg) * 2 + nh] = p[reg];
        }
        __syncthreads();   // T-layout reads done; sSS visible

        // ---------- normalize: v = o / max(||o||, 1e-12) ----------
        #pragma unroll
        for (int reg = 0; reg < 4; ++reg){
            int i = 16 * mt + 4 * q + reg;
            float ss = sSS[i * 2 + 0] + sSS[i * 2 + 1];
            float sc = 1.0f / fmaxf(sqrtf(ss), 1e-12f);
            #pragma unroll
            for (int tt = 0; tt < 4; ++tt)
                vreg[tt][reg] = o[tt][reg] * sc;
        }

        if (l < 2){
            // write v back split-bf16 in A-layout for next layer's phase 1
            #pragma unroll
            for (int tt = 0; tt < 4; ++tt){
                int j = 64 * nh + 16 * tt + l15;
                #pragma unroll
                for (int reg = 0; reg < 4; ++reg){
                    int i = 16 * mt + 4 * q + reg;
                    float v = vreg[tt][reg];
                    unsigned short h = f2bf(v);
                    sXhi[i * SK + j] = h;
                    sXlo[i * SK + j] = f2bf(v - bf2f(h));
                }
            }
            __syncthreads();
        }
    }

    // ---------- pooling: mol[j] = sum_i v[i][j] ----------
    float msum[4];
    #pragma unroll
    for (int tt = 0; tt < 4; ++tt){
        msum[tt] = vreg[tt][0] + vreg[tt][1] + vreg[tt][2] + vreg[tt][3];
        msum[tt] += __shfl_xor(msum[tt], 16);
        msum[tt] += __shfl_xor(msum[tt], 32);   // sum over this wave's 16 rows
    }
    if (q == 0){
        #pragma unroll
        for (int tt = 0; tt < 4; ++tt){
            int j = 64 * nh + 16 * tt + l15;
            sMolPart[mt * D + j] = msum[tt];
        }
    }
    __syncthreads();
    if (tid < D)
        sMolF[tid] = sMolPart[0 * D + tid] + sMolPart[1 * D + tid]
                   + sMolPart[2 * D + tid] + sMolPart[3 * D + tid];
    __syncthreads();

    // ---------- output MLP layer 1 (fp32) ----------
    if (tid < D){
        const float4* wr = (const float4*)&Wout[(0 * D + tid) * D];
        const float4* mv = (const float4*)sMolF;
        float s = 0.f;
        #pragma unroll
        for (int k = 0; k < 32; ++k){
            float4 w = wr[k], m = mv[k];
            s += w.x * m.x + w.y * m.y + w.z * m.z + w.w * m.w;
        }
        sY[tid] = gelu_f(s + Wob[tid]);
    }
    __syncthreads();
    // ---------- output MLP layer 2 + mask ----------
    if (tid < D){
        const float4* wr = (const float4*)&Wout[(1 * D + tid) * D];
        const float4* yv = (const float4*)sY;
        float s = 0.f;
        #pragma unroll
        for (int k = 0; k < 32; ++k){
            float4 w = wr[k], y = yv[k];
            s += w.x * y.x + w.y * y.y + w.z * y.z + w.w * y.w;
        }
        float z = gelu_f(s + Wob[D + tid]);
        out[blk * D + tid] = z * masks[blk];
    }
}

extern "C" void kernel_launch(void* const* d_in, const int* in_sizes, int n_in,
                              void* d_out, int out_size, void* d_ws, size_t ws_size,
                              hipStream_t stream) {
    const int*   fps = (const int*)  d_in[0];
    const float* adj = (const float*)d_in[1];
    const float* emb = (const float*)d_in[2];
    const float* Wfw = (const float*)d_in[3];
    const float* Wfb = (const float*)d_in[4];
    const float* Wow = (const float*)d_in[5];
    const float* Wob = (const float*)d_in[6];
    const float* msk = (const float*)d_in[7];

    unsigned short* Whi = (unsigned short*)d_ws;          // 3*128*128 bf16
    unsigned short* Wlo = Whi + 3 * D * D;                // 3*128*128 bf16
    const int nW = 3 * D * D;

    prep_w_split<<<(nW + 255) / 256, 256, 0, stream>>>(Wfw, Whi, Wlo, nW);
    mgnn_kernel<<<NMOL, 512, 0, stream>>>(fps, adj, emb, Whi, Wlo, Wfb,
                                          Wow, Wob, msk, (float*)d_out);
}

// Round 2
// 1158.757 us; speedup vs baseline: 1.0032x; 1.0032x over previous
//
#include <hip/hip_runtime.h>
#include <hip/hip_bf16.h>

// Problem constants (fixed by setup_inputs)
#define D    128      // feature dim
#define NPM  64       // nodes per molecule
#define NMOL 256      // molecules (= grid size = 1 block per CU)
#define NTOT 16384    // total nodes
#define SK   136      // LDS stride for A-layout (row-major v, bf16 elems)
#define ST   72       // LDS stride for T-layout (col-major h) and adjacency
#define SW   136      // LDS stride for weight planes (2-way bank alias = free)
#define XPLANE 9216   // max(64*SK=8704, 128*ST=9216) — hi/lo planes are aliased A/T

typedef __attribute__((ext_vector_type(8))) short bf16x8;
typedef __attribute__((ext_vector_type(4))) float f32x4;

__device__ __forceinline__ unsigned short f2bf(float x){
    union { float f; unsigned u; } c; c.f = x;
    unsigned r = c.u + 0x7FFFu + ((c.u >> 16) & 1u);  // RNE to bf16
    return (unsigned short)(r >> 16);
}
__device__ __forceinline__ float bf2f(unsigned short h){
    union { float f; unsigned u; } c; c.u = ((unsigned)h) << 16;
    return c.f;
}
// reference's tanh-approx GELU; tanh(z) = 1 - 2/(exp(2z)+1) is robust at both tails
__device__ __forceinline__ float gelu_f(float x){
    float z = 0.7978845608028654f * (x + 0.044715f * x * x * x);
    float e = __expf(2.0f * z);
    float t = 1.0f - 2.0f / (e + 1.0f);
    return 0.5f * x * (1.0f + t);
}

__global__ __launch_bounds__(512)
void mgnn_kernel(const int*   __restrict__ fps,
                 const float* __restrict__ adjacency,
                 const float* __restrict__ embed,
                 const float* __restrict__ Wfw,           // [3][128][128] fp32
                 const float* __restrict__ Wfb,           // [3][128]
                 const float* __restrict__ Wout,          // [2][128][128]
                 const float* __restrict__ Wob,           // [2][128]
                 const float* __restrict__ masks,         // [256]
                 float* __restrict__ out)                 // [256][128]
{
    __shared__ __attribute__((aligned(16))) unsigned short sXhi[XPLANE];
    __shared__ __attribute__((aligned(16))) unsigned short sXlo[XPLANE];
    __shared__ __attribute__((aligned(16))) unsigned short sWhi[D * SW];
    __shared__ __attribute__((aligned(16))) unsigned short sWlo[D * SW];
    __shared__ __attribute__((aligned(16))) unsigned short sAdj[NPM * ST];
    __shared__ int   sFp[NPM];
    __shared__ float sSS[NPM * 2];
    __shared__ float sMolPart[4 * D];
    __shared__ __attribute__((aligned(16))) float sMolF[D];
    __shared__ __attribute__((aligned(16))) float sY[D];

    const int tid  = threadIdx.x;
    const int blk  = blockIdx.x;
    const int lane = tid & 63;
    const int wave = tid >> 6;     // 8 waves
    const int l15  = lane & 15;
    const int q    = lane >> 4;    // quad 0..3
    const int mt   = wave & 3;     // m-tile (rows 16*mt..16*mt+15)
    const int nh   = wave >> 2;    // n-half (cols 64*nh..64*nh+63, 4 n-tiles)
    const int base = blk * NPM;

    // ---- stage fingerprints + adjacency diagonal block + W[0] split ----
    if (tid < NPM) sFp[tid] = fps[base + tid];
    #pragma unroll
    for (int u = 0; u < 8; ++u){
        int idx = tid + 512 * u;              // 4096 = 64x64 elements
        int r = idx >> 6, c = idx & 63;
        float a = adjacency[(size_t)(base + r) * NTOT + (base + c)];
        sAdj[r * ST + c] = f2bf(a);           // 0.0/1.0 exact
    }
    #pragma unroll
    for (int u = 0; u < 32; ++u){             // 16384 = 128x128
        int idx = tid + 512 * u;
        int n = idx >> 7, k = idx & 127;
        float w = Wfw[idx];                   // layer 0
        unsigned short h = f2bf(w);
        sWhi[n * SW + k] = h;
        sWlo[n * SW + k] = f2bf(w - bf2f(h));
    }
    __syncthreads();

    // ---- gather embeddings -> split bf16 hi/lo, A-layout [row][k] ----
    #pragma unroll
    for (int u = 0; u < 16; ++u){
        int idx = tid + 512 * u;              // 8192 = 64x128
        int r = idx >> 7, j = idx & 127;
        float v = embed[sFp[r] * D + j];
        unsigned short h = f2bf(v);
        sXhi[r * SK + j] = h;
        sXlo[r * SK + j] = f2bf(v - bf2f(h));
    }
    __syncthreads();

    const f32x4 zero4 = {0.f, 0.f, 0.f, 0.f};
    float vreg[4][4];                          // normalized v (for pooling)

    for (int l = 0; l < 3; ++l){
        // ---------- phase 1: H = v @ W^T (split-bf16, fp32 acc) ----------
        f32x4 acc[4] = {zero4, zero4, zero4, zero4};
        const int row_a = 16 * mt + l15;
        #pragma unroll
        for (int kt = 0; kt < 4; ++kt){
            int kb = kt * 32 + 8 * q;
            bf16x8 ahi = *(const bf16x8*)&sXhi[row_a * SK + kb];
            bf16x8 alo = *(const bf16x8*)&sXlo[row_a * SK + kb];
            #pragma unroll
            for (int tt = 0; tt < 4; ++tt){
                int n = 16 * (4 * nh + tt) + l15;
                bf16x8 bhi = *(const bf16x8*)&sWhi[n * SW + kb];
                bf16x8 blo = *(const bf16x8*)&sWlo[n * SW + kb];
                acc[tt] = __builtin_amdgcn_mfma_f32_16x16x32_bf16(ahi, bhi, acc[tt], 0, 0, 0);
                acc[tt] = __builtin_amdgcn_mfma_f32_16x16x32_bf16(alo, bhi, acc[tt], 0, 0, 0);
                acc[tt] = __builtin_amdgcn_mfma_f32_16x16x32_bf16(ahi, blo, acc[tt], 0, 0, 0);
            }
        }
        __syncthreads();   // A-layout + sW reads done before overwrite

        // ---------- epilogue: h = gelu(H + b); write split-T; prefetch W[l+1] ----------
        float hreg[4][4];
        #pragma unroll
        for (int tt = 0; tt < 4; ++tt){
            int j = 64 * nh + 16 * tt + l15;
            float bias = Wfb[l * D + j];
            #pragma unroll
            for (int reg = 0; reg < 4; ++reg){
                int i = 16 * mt + 4 * q + reg;
                float h = gelu_f(acc[tt][reg] + bias);
                hreg[tt][reg] = h;
                unsigned short hh = f2bf(h);
                sXhi[j * ST + i] = hh;                       // T-layout [col][node]
                sXlo[j * ST + i] = f2bf(h - bf2f(hh));
            }
        }
        if (l < 2){
            const float* Wl = Wfw + (l + 1) * D * D;
            #pragma unroll
            for (int u = 0; u < 32; ++u){
                int idx = tid + 512 * u;
                int n = idx >> 7, k = idx & 127;
                float w = Wl[idx];
                unsigned short h = f2bf(w);
                sWhi[n * SW + k] = h;
                sWlo[n * SW + k] = f2bf(w - bf2f(h));
            }
        }
        __syncthreads();   // T-layout + next-layer sW visible to all waves

        // ---------- phase 2: R = Adj @ h (Adj exact bf16; h split) ----------
        f32x4 racc[4] = {zero4, zero4, zero4, zero4};
        #pragma unroll
        for (int kt = 0; kt < 2; ++kt){
            int kb = kt * 32 + 8 * q;
            bf16x8 aadj = *(const bf16x8*)&sAdj[(16 * mt + l15) * ST + kb];
            #pragma unroll
            for (int tt = 0; tt < 4; ++tt){
                int n = 16 * (4 * nh + tt) + l15;
                bf16x8 bhi = *(const bf16x8*)&sXhi[n * ST + kb];
                bf16x8 blo = *(const bf16x8*)&sXlo[n * ST + kb];
                racc[tt] = __builtin_amdgcn_mfma_f32_16x16x32_bf16(aadj, bhi, racc[tt], 0, 0, 0);
                racc[tt] = __builtin_amdgcn_mfma_f32_16x16x32_bf16(aadj, blo, racc[tt], 0, 0, 0);
            }
        }

        // ---------- o = h + R; row sum-of-squares ----------
        float o[4][4];
        float p[4] = {0.f, 0.f, 0.f, 0.f};
        #pragma unroll
        for (int tt = 0; tt < 4; ++tt)
            #pragma unroll
            for (int reg = 0; reg < 4; ++reg){
                float v = hreg[tt][reg] + racc[tt][reg];
                o[tt][reg] = v;
                p[reg] += v * v;
            }
        #pragma unroll
        for (int d2 = 1; d2 <= 8; d2 <<= 1)
            #pragma unroll
            for (int reg = 0; reg < 4; ++reg)
                p[reg] += __shfl_xor(p[reg], d2);
        if (l15 == 0){
            #pragma unroll
            for (int reg = 0; reg < 4; ++reg)
                sSS[(16 * mt + 4 * q + reg) * 2 + nh] = p[reg];
        }
        __syncthreads();   // T-layout reads done; sSS visible

        // ---------- normalize: v = o / max(||o||, 1e-12) ----------
        #pragma unroll
        for (int reg = 0; reg < 4; ++reg){
            int i = 16 * mt + 4 * q + reg;
            float ss = sSS[i * 2 + 0] + sSS[i * 2 + 1];
            float sc = 1.0f / fmaxf(sqrtf(ss), 1e-12f);
            #pragma unroll
            for (int tt = 0; tt < 4; ++tt)
                vreg[tt][reg] = o[tt][reg] * sc;
        }

        if (l < 2){
            // write v back split-bf16 in A-layout for next layer's phase 1
            #pragma unroll
            for (int tt = 0; tt < 4; ++tt){
                int j = 64 * nh + 16 * tt + l15;
                #pragma unroll
                for (int reg = 0; reg < 4; ++reg){
                    int i = 16 * mt + 4 * q + reg;
                    float v = vreg[tt][reg];
                    unsigned short h = f2bf(v);
                    sXhi[i * SK + j] = h;
                    sXlo[i * SK + j] = f2bf(v - bf2f(h));
                }
            }
            __syncthreads();
        }
    }

    // ---------- pooling: mol[j] = sum_i v[i][j] ----------
    float msum[4];
    #pragma unroll
    for (int tt = 0; tt < 4; ++tt){
        msum[tt] = vreg[tt][0] + vreg[tt][1] + vreg[tt][2] + vreg[tt][3];
        msum[tt] += __shfl_xor(msum[tt], 16);
        msum[tt] += __shfl_xor(msum[tt], 32);   // sum over this wave's 16 rows
    }
    if (q == 0){
        #pragma unroll
        for (int tt = 0; tt < 4; ++tt){
            int j = 64 * nh + 16 * tt + l15;
            sMolPart[mt * D + j] = msum[tt];
        }
    }
    __syncthreads();
    if (tid < D)
        sMolF[tid] = sMolPart[0 * D + tid] + sMolPart[1 * D + tid]
                   + sMolPart[2 * D + tid] + sMolPart[3 * D + tid];
    __syncthreads();

    // ---------- output MLP layer 1 (fp32) ----------
    if (tid < D){
        const float4* wr = (const float4*)&Wout[(0 * D + tid) * D];
        const float4* mv = (const float4*)sMolF;
        float s = 0.f;
        #pragma unroll
        for (int k = 0; k < 32; ++k){
            float4 w = wr[k], m = mv[k];
            s += w.x * m.x + w.y * m.y + w.z * m.z + w.w * m.w;
        }
        sY[tid] = gelu_f(s + Wob[tid]);
    }
    __syncthreads();
    // ---------- output MLP layer 2 + mask ----------
    if (tid < D){
        const float4* wr = (const float4*)&Wout[(1 * D + tid) * D];
        const float4* yv = (const float4*)sY;
        float s = 0.f;
        #pragma unroll
        for (int k = 0; k < 32; ++k){
            float4 w = wr[k], y = yv[k];
            s += w.x * y.x + w.y * y.y + w.z * y.z + w.w * y.w;
        }
        float z = gelu_f(s + Wob[D + tid]);
        out[blk * D + tid] = z * masks[blk];
    }
}

extern "C" void kernel_launch(void* const* d_in, const int* in_sizes, int n_in,
                              void* d_out, int out_size, void* d_ws, size_t ws_size,
                              hipStream_t stream) {
    const int*   fps = (const int*)  d_in[0];
    const float* adj = (const float*)d_in[1];
    const float* emb = (const float*)d_in[2];
    const float* Wfw = (const float*)d_in[3];
    const float* Wfb = (const float*)d_in[4];
    const float* Wow = (const float*)d_in[5];
    const float* Wob = (const float*)d_in[6];
    const float* msk = (const float*)d_in[7];

    mgnn_kernel<<<NMOL, 512, 0, stream>>>(fps, adj, emb, Wfw, Wfb,
                                          Wow, Wob, msk, (float*)d_out);
}